// Round 1
// baseline (671.883 us; speedup 1.0000x reference)
//
#include <hip/hip_runtime.h>

#define N 4096
#define CC 256
#define CH 32
#define NSPLIT 4
#define SPLEN (N / NSPLIT)

// ---- workspace float offsets ----
#define OFF_WT6   0            // wt6   [6][256][32]   transposed f/g/h weights [q][c][ch]
#define OFF_WOT   49152        // wot   [2][512][256]  transposed wo [r][j][o]
#define OFF_WEFF  311296       // weff  [2][64][256]   Weff_t [r][ch][o]
#define OFF_BEFF  344064       // beff  [2][256]
#define OFF_FGH   344576       // fgh   [6][2][4096][32]  q: 0=f1 1=g1 2=h1 3=f2 4=g2 5=h2
#define OFF_P     1917440      // Pacc  [8][4][32][4096]  (ib, split, c, m)
#define OFF_L     6111744      // Lsum  [8][4][4096]
#define OFF_AOT   6242816      // aot   [8][32][4096]     (ib, c, m)

// ------------------------------------------------------------------
// 1) transpose small weight matrices for coalesced / scalar access
// ------------------------------------------------------------------
__global__ void k_transpose(const float* __restrict__ wf1, const float* __restrict__ wg1,
                            const float* __restrict__ wh1, const float* __restrict__ wf2,
                            const float* __restrict__ wg2, const float* __restrict__ wh2,
                            const float* __restrict__ wo1, const float* __restrict__ wo2,
                            float* __restrict__ wt6, float* __restrict__ wot) {
  int bid = blockIdx.x;
  if (bid < 192) {
    int idx = bid * 256 + threadIdx.x;                 // < 49152
    int ch = idx & 31, c = (idx >> 5) & 255, q = idx >> 13;
    const float* w = q == 0 ? wf1 : q == 1 ? wg1 : q == 2 ? wh1
                   : q == 3 ? wf2 : q == 4 ? wg2 : wh2;
    wt6[idx] = w[ch * CC + c];
  } else {
    int idx = (bid - 192) * 256 + threadIdx.x;         // < 262144
    int o = idx & 255, j = (idx >> 8) & 511, r = idx >> 17;
    const float* wo = r == 0 ? wo1 : wo2;
    wot[idx] = wo[o * 512 + j];
  }
}

// ------------------------------------------------------------------
// 2) Weff_t[r][ch][o] = sum_c wo_r[o][half*256+c] * wv_{r,half}[c][ch%32]
//    beff[r][o]       = bo_r[o] + sum wo_r[o][:]*bv_cat[:]
// ------------------------------------------------------------------
__global__ void k_weff(const float* __restrict__ wot,
                       const float* __restrict__ wv11, const float* __restrict__ wv12,
                       const float* __restrict__ wv21, const float* __restrict__ wv22,
                       const float* __restrict__ bv11, const float* __restrict__ bv12,
                       const float* __restrict__ bv21, const float* __restrict__ bv22,
                       const float* __restrict__ bo1, const float* __restrict__ bo2,
                       float* __restrict__ weff, float* __restrict__ beff) {
  int bid = blockIdx.x;
  int o = threadIdx.x;
  if (bid < 128) {
    int r = bid >> 6, ch = bid & 63, half = ch >> 5, chp = ch & 31;
    const float* wv = (r == 0) ? (half ? wv12 : wv11) : (half ? wv22 : wv21);
    const float* wocol = wot + ((size_t)r * 512 + half * 256) * 256 + o;
    float a = 0.f;
    for (int c = 0; c < 256; ++c)
      a = fmaf(wocol[(size_t)c * 256], wv[c * CH + chp], a);
    weff[((size_t)r * 64 + ch) * 256 + o] = a;
  } else {
    int r = bid - 128;
    const float* bo  = r == 0 ? bo1 : bo2;
    const float* bva = r == 0 ? bv11 : bv21;
    const float* bvb = r == 0 ? bv12 : bv22;
    const float* wocol = wot + (size_t)r * 512 * 256 + o;
    float a = bo[o];
    for (int c = 0; c < 256; ++c) {
      a = fmaf(wocol[(size_t)c * 256], bva[c], a);
      a = fmaf(wocol[(size_t)(c + 256) * 256], bvb[c], a);
    }
    beff[r * 256 + o] = a;
  }
}

// ------------------------------------------------------------------
// 3) projections: fgh[q][b][n][ch] = sum_c wt6[q][c][ch]*src[b][c][n] + bias
//    64 threads = 64 n; weights read wave-uniform (-> s_load)
// ------------------------------------------------------------------
__global__ __launch_bounds__(64) void k_proj(
    const float* __restrict__ x, const float* __restrict__ y,
    const float* __restrict__ wt6,
    const float* __restrict__ bf1, const float* __restrict__ bg1, const float* __restrict__ bh1,
    const float* __restrict__ bf2, const float* __restrict__ bg2, const float* __restrict__ bh2,
    float* __restrict__ fgh) {
  int nt = blockIdx.x & 63;
  int bq = blockIdx.x >> 6;
  int q = bq % 6, b = bq / 6;
  const float* src = (q == 3 || q == 4) ? y : x;     // f2,g2 from y; h2 from x
  src += (size_t)b * CC * N + nt * 64 + threadIdx.x;
  const float* wt = wt6 + (size_t)q * CC * CH;
  float acc[CH];
#pragma unroll
  for (int ch = 0; ch < CH; ++ch) acc[ch] = 0.f;
  for (int c = 0; c < CC; ++c) {
    float xv = src[(size_t)c * N];
    const float* wr = wt + c * CH;
#pragma unroll
    for (int ch = 0; ch < CH; ++ch) acc[ch] = fmaf(wr[ch], xv, acc[ch]);
  }
  const float* bias = q == 0 ? bf1 : q == 1 ? bg1 : q == 2 ? bh1
                    : q == 3 ? bf2 : q == 4 ? bg2 : bh2;
  int n = nt * 64 + threadIdx.x;
  float* out = fgh + ((size_t)(q * 2 + b) * N + n) * CH;
  float4* o4 = (float4*)out;
#pragma unroll
  for (int j = 0; j < 8; ++j)
    o4[j] = make_float4(acc[4 * j] + bias[4 * j], acc[4 * j + 1] + bias[4 * j + 1],
                        acc[4 * j + 2] + bias[4 * j + 2], acc[4 * j + 3] + bias[4 * j + 3]);
}

// ------------------------------------------------------------------
// 4) flash attention, no-max softmax (scores bounded; shift by 15 cancels)
//    1 query row / thread, KV split 4-way. K/V rows wave-uniform -> s_load.
// ------------------------------------------------------------------
__global__ __launch_bounds__(64) void k_attn(const float* __restrict__ fgh,
                                             float* __restrict__ Pacc,
                                             float* __restrict__ Lsum) {
  int bid = blockIdx.x;
  int s = bid & 3, rt = (bid >> 2) & 63, b = (bid >> 8) & 1, i = bid >> 9;
  int ia = i >> 1, ibk = i & 1;                      // pair (a,b): Q=f_a, K=g_b, V=h_b
  const float* Q = fgh + (size_t)((ia  == 0 ? 0 : 3) * 2 + b) * N * CH;
  const float* K = fgh + (size_t)((ibk == 0 ? 1 : 4) * 2 + b) * N * CH;
  const float* V = fgh + (size_t)((ibk == 0 ? 2 : 5) * 2 + b) * N * CH;

  int m = rt * 64 + threadIdx.x;
  float q[CH];
  const float4* qp = (const float4*)(Q + (size_t)m * CH);
#pragma unroll
  for (int j = 0; j < 8; ++j) {
    float4 v4 = qp[j];
    q[4 * j] = v4.x; q[4 * j + 1] = v4.y; q[4 * j + 2] = v4.z; q[4 * j + 3] = v4.w;
  }
  float acc[CH];
#pragma unroll
  for (int c = 0; c < CH; ++c) acc[c] = 0.f;
  float l = 0.f;

  int n0 = s * SPLEN;
  for (int n = n0; n < n0 + SPLEN; ++n) {
    const float* kr = K + (size_t)n * CH;
    float s0 = 0.f, s1 = 0.f, s2 = 0.f, s3 = 0.f;
#pragma unroll
    for (int c = 0; c < CH; c += 4) {
      s0 = fmaf(q[c],     kr[c],     s0);
      s1 = fmaf(q[c + 1], kr[c + 1], s1);
      s2 = fmaf(q[c + 2], kr[c + 2], s2);
      s3 = fmaf(q[c + 3], kr[c + 3], s3);
    }
    float sv = (s0 + s1) + (s2 + s3);
    float p = __expf(sv - 15.0f);
    l += p;
    const float* vr = V + (size_t)n * CH;
#pragma unroll
    for (int c = 0; c < CH; ++c) acc[c] = fmaf(p, vr[c], acc[c]);
  }

  int ib = i * 2 + b;
  float* pout = Pacc + (size_t)(ib * NSPLIT + s) * CH * N + m;
#pragma unroll
  for (int c = 0; c < CH; ++c) pout[(size_t)c * N] = acc[c];
  Lsum[(size_t)(ib * NSPLIT + s) * N + m] = l;
}

// ------------------------------------------------------------------
// 5) combine splits: aot[ib][c][m] = sum_s P / sum_s L
// ------------------------------------------------------------------
__global__ void k_combine(const float* __restrict__ Pacc, const float* __restrict__ Lsum,
                          float* __restrict__ aot) {
  int idx = blockIdx.x * 256 + threadIdx.x;          // 8*32*4096
  int m = idx & (N - 1), c = (idx >> 12) & 31, ib = idx >> 17;
  float a = 0.f, l = 0.f;
#pragma unroll
  for (int s = 0; s < NSPLIT; ++s) {
    a += Pacc[(size_t)(ib * NSPLIT + s) * CH * N + (size_t)c * N + m];
    l += Lsum[(size_t)(ib * NSPLIT + s) * N + m];
  }
  aot[(size_t)(ib * CH + c) * N + m] = a / l;
}

// ------------------------------------------------------------------
// 6) epilogue: out[r][b][o][m] = src[b][o][m] + sum_ch Weff_t[r][ch][o]*AO_cat + beff
// ------------------------------------------------------------------
__global__ __launch_bounds__(64) void k_epi(const float* __restrict__ x, const float* __restrict__ y,
                                            const float* __restrict__ aot,
                                            const float* __restrict__ weff,
                                            const float* __restrict__ beff,
                                            float* __restrict__ out) {
  int bid = blockIdx.x;
  int mt = bid & 63, og = (bid >> 6) & 15, b = (bid >> 10) & 1, r = bid >> 11;
  int m = mt * 64 + threadIdx.x;
  int o0 = og * 16;
  const float* src = r == 0 ? x : y;
  const float* A0 = aot + (size_t)(r * 4 + b) * CH * N;        // instance (r,0)
  const float* A1 = aot + (size_t)(r * 4 + 2 + b) * CH * N;    // instance (r,1)
  const float* wrow = weff + (size_t)r * 64 * 256;
  float acc[16];
#pragma unroll
  for (int j = 0; j < 16; ++j) acc[j] = 0.f;
#pragma unroll 4
  for (int ch = 0; ch < 32; ++ch) {
    float av = A0[(size_t)ch * N + m];
    const float* wr = wrow + ch * 256 + o0;
#pragma unroll
    for (int j = 0; j < 16; ++j) acc[j] = fmaf(wr[j], av, acc[j]);
  }
#pragma unroll 4
  for (int ch = 0; ch < 32; ++ch) {
    float av = A1[(size_t)ch * N + m];
    const float* wr = wrow + (32 + ch) * 256 + o0;
#pragma unroll
    for (int j = 0; j < 16; ++j) acc[j] = fmaf(wr[j], av, acc[j]);
  }
  float* outr = out + (size_t)r * 2 * CC * N;
#pragma unroll
  for (int j = 0; j < 16; ++j) {
    int o = o0 + j;
    size_t off = ((size_t)b * CC + o) * N + m;
    outr[off] = src[off] + acc[j] + beff[r * CC + o];
  }
}

extern "C" void kernel_launch(void* const* d_in, const int* in_sizes, int n_in,
                              void* d_out, int out_size, void* d_ws, size_t ws_size,
                              hipStream_t stream) {
  const float* x    = (const float*)d_in[0];
  const float* y    = (const float*)d_in[1];
  const float* wf1  = (const float*)d_in[2];
  const float* bf1  = (const float*)d_in[3];
  const float* wg1  = (const float*)d_in[4];
  const float* bg1  = (const float*)d_in[5];
  const float* wh1  = (const float*)d_in[6];
  const float* bh1  = (const float*)d_in[7];
  const float* wf2  = (const float*)d_in[8];
  const float* bf2  = (const float*)d_in[9];
  const float* wg2  = (const float*)d_in[10];
  const float* bg2  = (const float*)d_in[11];
  const float* wh2  = (const float*)d_in[12];
  const float* bh2  = (const float*)d_in[13];
  const float* wv11 = (const float*)d_in[14];
  const float* bv11 = (const float*)d_in[15];
  const float* wv12 = (const float*)d_in[16];
  const float* bv12 = (const float*)d_in[17];
  const float* wv21 = (const float*)d_in[18];
  const float* bv21 = (const float*)d_in[19];
  const float* wv22 = (const float*)d_in[20];
  const float* bv22 = (const float*)d_in[21];
  const float* wo1  = (const float*)d_in[22];
  const float* bo1  = (const float*)d_in[23];
  const float* wo2  = (const float*)d_in[24];
  const float* bo2  = (const float*)d_in[25];

  float* ws   = (float*)d_ws;
  float* wt6  = ws + OFF_WT6;
  float* wot  = ws + OFF_WOT;
  float* weff = ws + OFF_WEFF;
  float* beff = ws + OFF_BEFF;
  float* fgh  = ws + OFF_FGH;
  float* P    = ws + OFF_P;
  float* L    = ws + OFF_L;
  float* aot  = ws + OFF_AOT;
  float* out  = (float*)d_out;

  k_transpose<<<1216, 256, 0, stream>>>(wf1, wg1, wh1, wf2, wg2, wh2, wo1, wo2, wt6, wot);
  k_weff<<<130, 256, 0, stream>>>(wot, wv11, wv12, wv21, wv22,
                                  bv11, bv12, bv21, bv22, bo1, bo2, weff, beff);
  k_proj<<<768, 64, 0, stream>>>(x, y, wt6, bf1, bg1, bh1, bf2, bg2, bh2, fgh);
  k_attn<<<2048, 64, 0, stream>>>(fgh, P, L);
  k_combine<<<4096, 256, 0, stream>>>(P, L, aot);
  k_epi<<<4096, 64, 0, stream>>>(x, y, aot, weff, beff, out);
}

// Round 2
// 130.720 us; speedup vs baseline: 5.1399x; 5.1399x over previous
//
#include <hip/hip_runtime.h>
#include <hip/hip_bf16.h>
#include <cstdint>

#define N 4096
#define CC 256
#define CH 32
#define L2E 1.4426950408889634f
#define CSHIFT 21.640425613334453f   // 15 * log2(e)

typedef __attribute__((ext_vector_type(8)))  short short8;
typedef __attribute__((ext_vector_type(16))) float f32x16;
typedef __attribute__((ext_vector_type(4)))  uint32_t u32x4;

// ---- workspace float offsets ----
#define OFF_WT6   0            // wt6   [6][256][32] fp32
#define OFF_WOT   49152        // wot   [2][512][256] fp32
#define OFF_WEFF  311296       // weff  [2][64][256] fp32
#define OFF_BEFF  344064       // beff  [2][256] fp32
#define OFF_QB    344576       // Qb    [2][2][4096][32] bf16  (f1,f2 scaled by log2e)
#define OFF_KB    606720       // Kb    [2][2][4096][32] bf16  (g1,g2)
#define OFF_VT    868864       // Vt    [2][2][32][4096] bf16  (h1,h2 transposed)
#define OFF_P2    1131008      // Pacc  [8][2][4096][32] fp32  (ib, split, q, ch) unnormalized
#define OFF_L2    3228160      // Lsum  [8][2][4096]
#define OFF_AOT   3293696      // aot   [8][32][4096] fp32

__device__ __forceinline__ uint32_t cvtpk_bf16(float lo, float hi) {
  uint32_t r;
  asm("v_cvt_pk_bf16_f32 %0, %1, %2" : "=v"(r) : "v"(lo), "v"(hi));
  return r;
}

// ------------------------------------------------------------------
// 1) transpose small weight matrices
// ------------------------------------------------------------------
__global__ void k_transpose(const float* __restrict__ wf1, const float* __restrict__ wg1,
                            const float* __restrict__ wh1, const float* __restrict__ wf2,
                            const float* __restrict__ wg2, const float* __restrict__ wh2,
                            const float* __restrict__ wo1, const float* __restrict__ wo2,
                            float* __restrict__ wt6, float* __restrict__ wot) {
  int bid = blockIdx.x;
  if (bid < 192) {
    int idx = bid * 256 + threadIdx.x;                 // < 49152
    int ch = idx & 31, c = (idx >> 5) & 255, q = idx >> 13;
    const float* w = q == 0 ? wf1 : q == 1 ? wg1 : q == 2 ? wh1
                   : q == 3 ? wf2 : q == 4 ? wg2 : wh2;
    wt6[idx] = w[ch * CC + c];
  } else {
    int idx = (bid - 192) * 256 + threadIdx.x;         // < 262144
    int o = idx & 255, j = (idx >> 8) & 511, r = idx >> 17;
    const float* wo = r == 0 ? wo1 : wo2;
    wot[idx] = wo[o * 512 + j];
  }
}

// ------------------------------------------------------------------
// 2) effective epilogue weights: Weff = wo * [wv_a; wv_b], beff = bo + wo*bv
// ------------------------------------------------------------------
__global__ void k_weff(const float* __restrict__ wot,
                       const float* __restrict__ wv11, const float* __restrict__ wv12,
                       const float* __restrict__ wv21, const float* __restrict__ wv22,
                       const float* __restrict__ bv11, const float* __restrict__ bv12,
                       const float* __restrict__ bv21, const float* __restrict__ bv22,
                       const float* __restrict__ bo1, const float* __restrict__ bo2,
                       float* __restrict__ weff, float* __restrict__ beff) {
  int bid = blockIdx.x;
  int o = threadIdx.x;
  if (bid < 128) {
    int r = bid >> 6, ch = bid & 63, half = ch >> 5, chp = ch & 31;
    const float* wv = (r == 0) ? (half ? wv12 : wv11) : (half ? wv22 : wv21);
    const float* wocol = wot + ((size_t)r * 512 + half * 256) * 256 + o;
    float a = 0.f;
    for (int c = 0; c < 256; ++c)
      a = fmaf(wocol[(size_t)c * 256], wv[c * CH + chp], a);
    weff[((size_t)r * 64 + ch) * 256 + o] = a;
  } else {
    int r = bid - 128;
    const float* bo  = r == 0 ? bo1 : bo2;
    const float* bva = r == 0 ? bv11 : bv21;
    const float* bvb = r == 0 ? bv12 : bv22;
    const float* wocol = wot + (size_t)r * 512 * 256 + o;
    float a = bo[o];
    for (int c = 0; c < 256; ++c) {
      a = fmaf(wocol[(size_t)c * 256], bva[c], a);
      a = fmaf(wocol[(size_t)(c + 256) * 256], bvb[c], a);
    }
    beff[r * 256 + o] = a;
  }
}

// ------------------------------------------------------------------
// 3) projections -> bf16. f* scaled by log2e (so attn exp is one v_exp).
//    Q/K: [inst][b][n][32] row-major; V: [inst][b][32][4096] transposed.
// ------------------------------------------------------------------
__global__ __launch_bounds__(64) void k_proj(
    const float* __restrict__ x, const float* __restrict__ y,
    const float* __restrict__ wt6,
    const float* __restrict__ bf1, const float* __restrict__ bg1, const float* __restrict__ bh1,
    const float* __restrict__ bf2, const float* __restrict__ bg2, const float* __restrict__ bh2,
    uint16_t* __restrict__ Qb, uint16_t* __restrict__ Kb, uint16_t* __restrict__ Vt) {
  int nt = blockIdx.x & 63;
  int bq = blockIdx.x >> 6;
  int q = bq % 6, b = bq / 6;
  const float* src = (q == 3 || q == 4) ? y : x;     // f2,g2 from y; h1,h2 from x
  src += (size_t)b * CC * N + nt * 64 + threadIdx.x;
  const float* wt = wt6 + (size_t)q * CC * CH;
  float acc[CH];
#pragma unroll
  for (int ch = 0; ch < CH; ++ch) acc[ch] = 0.f;
#pragma unroll 4
  for (int c = 0; c < CC; ++c) {
    float xv = src[(size_t)c * N];
    const float* wr = wt + c * CH;
#pragma unroll
    for (int ch = 0; ch < CH; ++ch) acc[ch] = fmaf(wr[ch], xv, acc[ch]);
  }
  const float* bias = q == 0 ? bf1 : q == 1 ? bg1 : q == 2 ? bh1
                    : q == 3 ? bf2 : q == 4 ? bg2 : bh2;
  int n = nt * 64 + threadIdx.x;
  float v[CH];
  bool isf = (q == 0 || q == 3);
#pragma unroll
  for (int ch = 0; ch < CH; ++ch) {
    float t = acc[ch] + bias[ch];
    v[ch] = isf ? t * L2E : t;
  }
  if (q == 0 || q == 3) {
    uint16_t* out = Qb + ((size_t)(((q == 3) * 2 + b) * N + n)) * CH;
    u32x4* o4 = (u32x4*)out;
#pragma unroll
    for (int j = 0; j < 4; ++j) {
      u32x4 pk;
#pragma unroll
      for (int k = 0; k < 4; ++k) pk[k] = cvtpk_bf16(v[j * 8 + 2 * k], v[j * 8 + 2 * k + 1]);
      o4[j] = pk;
    }
  } else if (q == 1 || q == 4) {
    uint16_t* out = Kb + ((size_t)(((q == 4) * 2 + b) * N + n)) * CH;
    u32x4* o4 = (u32x4*)out;
#pragma unroll
    for (int j = 0; j < 4; ++j) {
      u32x4 pk;
#pragma unroll
      for (int k = 0; k < 4; ++k) pk[k] = cvtpk_bf16(v[j * 8 + 2 * k], v[j * 8 + 2 * k + 1]);
      o4[j] = pk;
    }
  } else {
    uint16_t* out = Vt + (size_t)(((q == 5) * 2 + b) * CH) * N + n;
#pragma unroll
    for (int ch = 0; ch < CH; ++ch) {
      __hip_bfloat16 h = __float2bfloat16(v[ch]);
      out[(size_t)ch * N] = *reinterpret_cast<uint16_t*>(&h);
    }
  }
}

// ------------------------------------------------------------------
// 4) MFMA flash attention, 32x32x16 bf16, swapped QK^T.
//    1 wave / block, 32 queries / wave, KV split 2-way, no LDS/barriers.
//    S^T = mfma(K, Q^T): lane holds P[q=lane&31][16 of 32 keys]
//    (row = (reg&3)+8*(reg>>2)+4*(lane>>5)). P->bf16 A-frag via
//    cvt_pk + permlane32_swap. PV: AO += mfma(P, V) with Vt rows.
// ------------------------------------------------------------------
__global__ __launch_bounds__(64) void k_attn2(const uint16_t* __restrict__ Qb,
                                              const uint16_t* __restrict__ Kb,
                                              const uint16_t* __restrict__ Vt,
                                              float* __restrict__ Pacc,
                                              float* __restrict__ Lsum) {
  int bid = blockIdx.x;
  int s = bid & 1, qt = (bid >> 1) & 127, b = (bid >> 8) & 1, i = bid >> 9;
  int ia = i >> 1, ik = i & 1;                       // Q=f_ia, K=g_ik, V=h_ik
  int l = threadIdx.x, l31 = l & 31, l5 = l >> 5;

  const uint16_t* Qp = Qb + (size_t)((ia * 2 + b) * N + qt * 32) * CH;
  const uint16_t* Kp = Kb + (size_t)((ik * 2 + b) * N + s * (N / 2)) * CH;
  const uint16_t* Vp = Vt + (size_t)(ik * 2 + b) * CH * N + (size_t)l31 * N + s * (N / 2);

  // Q B-frags: B[ch][q], lane holds Q[q=l31][ch = h*16 + l5*8 + j]
  short8 bq0 = *(const short8*)(Qp + l31 * CH + l5 * 8);
  short8 bq1 = *(const short8*)(Qp + l31 * CH + 16 + l5 * 8);

  f32x16 cinit, ao;
#pragma unroll
  for (int r = 0; r < 16; ++r) { cinit[r] = -CSHIFT; ao[r] = 0.f; }
  float lacc = 0.f;

  for (int t = 0; t < (N / 2) / 32; ++t) {
    const uint16_t* kt = Kp + (size_t)t * 32 * CH;
    short8 ak0 = *(const short8*)(kt + l31 * CH + l5 * 8);
    short8 ak1 = *(const short8*)(kt + l31 * CH + 16 + l5 * 8);
    const uint16_t* vp = Vp + t * 32;
    short8 bv0 = *(const short8*)(vp + l5 * 8);
    short8 bv1 = *(const short8*)(vp + 16 + l5 * 8);

    // S^T tile (32 keys x 32 queries), C-init = -15*log2e
    f32x16 sa = __builtin_amdgcn_mfma_f32_32x32x16_bf16(ak0, bq0, cinit, 0, 0, 0);
    sa = __builtin_amdgcn_mfma_f32_32x32x16_bf16(ak1, bq1, sa, 0, 0, 0);

    float p[16];
#pragma unroll
    for (int r = 0; r < 16; ++r) p[r] = exp2f(sa[r]);

    float t0 = 0.f, t1 = 0.f;
#pragma unroll
    for (int r = 0; r < 8; ++r) { t0 += p[2 * r]; t1 += p[2 * r + 1]; }
    lacc += t0 + t1;

    // P -> bf16 A-frags (keys 0..15 and 16..31)
    uint32_t w[8];
#pragma unroll
    for (int kh = 0; kh < 2; ++kh) {
      int base = kh * 8;
      uint32_t x0 = cvtpk_bf16(p[base + 0], p[base + 1]);
      uint32_t y0 = cvtpk_bf16(p[base + 4], p[base + 5]);
      asm volatile("v_permlane32_swap_b32 %0, %1" : "+v"(x0), "+v"(y0));
      uint32_t x1 = cvtpk_bf16(p[base + 2], p[base + 3]);
      uint32_t y1 = cvtpk_bf16(p[base + 6], p[base + 7]);
      asm volatile("v_permlane32_swap_b32 %0, %1" : "+v"(x1), "+v"(y1));
      w[kh * 4 + 0] = x0; w[kh * 4 + 1] = x1; w[kh * 4 + 2] = y0; w[kh * 4 + 3] = y1;
    }
    u32x4 u0 = {w[0], w[1], w[2], w[3]};
    u32x4 u1 = {w[4], w[5], w[6], w[7]};
    short8 pa0 = __builtin_bit_cast(short8, u0);
    short8 pa1 = __builtin_bit_cast(short8, u1);

    ao = __builtin_amdgcn_mfma_f32_32x32x16_bf16(pa0, bv0, ao, 0, 0, 0);
    ao = __builtin_amdgcn_mfma_f32_32x32x16_bf16(pa1, bv1, ao, 0, 0, 0);
  }

  int ib = i * 2 + b;
  float* po = Pacc + (size_t)((ib * 2 + s) * N + qt * 32) * CH + l31;
#pragma unroll
  for (int r = 0; r < 16; ++r) {
    int row = (r & 3) + 8 * (r >> 2) + 4 * l5;       // query within tile
    po[(size_t)row * CH] = ao[r];
  }
  lacc += __shfl_xor(lacc, 32);
  if (l < 32) Lsum[(size_t)(ib * 2 + s) * N + qt * 32 + l31] = lacc;
}

// ------------------------------------------------------------------
// 5) combine splits + normalize + transpose to aot[ib][ch][q]
// ------------------------------------------------------------------
__global__ void k_combine(const float* __restrict__ Pacc, const float* __restrict__ Lsum,
                          float* __restrict__ aot) {
  int idx = blockIdx.x * 256 + threadIdx.x;          // 8*4096
  int q = idx & (N - 1), ib = idx >> 12;
  const float* p0 = Pacc + (size_t)(ib * 2) * N * CH + (size_t)q * CH;
  const float* p1 = p0 + (size_t)N * CH;
  float lv = Lsum[(size_t)(ib * 2) * N + q] + Lsum[(size_t)(ib * 2 + 1) * N + q];
  float inv = 1.f / lv;
#pragma unroll
  for (int c = 0; c < CH; c += 4) {
    float4 a = *(const float4*)(p0 + c);
    float4 b4 = *(const float4*)(p1 + c);
    aot[((size_t)ib * CH + c + 0) * N + q] = (a.x + b4.x) * inv;
    aot[((size_t)ib * CH + c + 1) * N + q] = (a.y + b4.y) * inv;
    aot[((size_t)ib * CH + c + 2) * N + q] = (a.z + b4.z) * inv;
    aot[((size_t)ib * CH + c + 3) * N + q] = (a.w + b4.w) * inv;
  }
}

// ------------------------------------------------------------------
// 6) epilogue: out[r][b][o][m] = src + Weff * AO_cat + beff
// ------------------------------------------------------------------
__global__ __launch_bounds__(64) void k_epi(const float* __restrict__ x, const float* __restrict__ y,
                                            const float* __restrict__ aot,
                                            const float* __restrict__ weff,
                                            const float* __restrict__ beff,
                                            float* __restrict__ out) {
  int bid = blockIdx.x;
  int mt = bid & 63, og = (bid >> 6) & 15, b = (bid >> 10) & 1, r = bid >> 11;
  int m = mt * 64 + threadIdx.x;
  int o0 = og * 16;
  const float* src = r == 0 ? x : y;
  const float* A0 = aot + (size_t)(r * 4 + b) * CH * N;        // instance (r, ik=0)
  const float* A1 = aot + (size_t)(r * 4 + 2 + b) * CH * N;    // instance (r, ik=1)
  const float* wrow = weff + (size_t)r * 64 * 256;
  float acc[16];
#pragma unroll
  for (int j = 0; j < 16; ++j) acc[j] = 0.f;
#pragma unroll 4
  for (int ch = 0; ch < 32; ++ch) {
    float av = A0[(size_t)ch * N + m];
    const float* wr = wrow + ch * 256 + o0;
#pragma unroll
    for (int j = 0; j < 16; ++j) acc[j] = fmaf(wr[j], av, acc[j]);
  }
#pragma unroll 4
  for (int ch = 0; ch < 32; ++ch) {
    float av = A1[(size_t)ch * N + m];
    const float* wr = wrow + (32 + ch) * 256 + o0;
#pragma unroll
    for (int j = 0; j < 16; ++j) acc[j] = fmaf(wr[j], av, acc[j]);
  }
  float* outr = out + (size_t)r * 2 * CC * N;
#pragma unroll
  for (int j = 0; j < 16; ++j) {
    int o = o0 + j;
    size_t off = ((size_t)b * CC + o) * N + m;
    outr[off] = src[off] + acc[j] + beff[r * CC + o];
  }
}

extern "C" void kernel_launch(void* const* d_in, const int* in_sizes, int n_in,
                              void* d_out, int out_size, void* d_ws, size_t ws_size,
                              hipStream_t stream) {
  const float* x    = (const float*)d_in[0];
  const float* y    = (const float*)d_in[1];
  const float* wf1  = (const float*)d_in[2];
  const float* bf1  = (const float*)d_in[3];
  const float* wg1  = (const float*)d_in[4];
  const float* bg1  = (const float*)d_in[5];
  const float* wh1  = (const float*)d_in[6];
  const float* bh1  = (const float*)d_in[7];
  const float* wf2  = (const float*)d_in[8];
  const float* bf2  = (const float*)d_in[9];
  const float* wg2  = (const float*)d_in[10];
  const float* bg2  = (const float*)d_in[11];
  const float* wh2  = (const float*)d_in[12];
  const float* bh2  = (const float*)d_in[13];
  const float* wv11 = (const float*)d_in[14];
  const float* bv11 = (const float*)d_in[15];
  const float* wv12 = (const float*)d_in[16];
  const float* bv12 = (const float*)d_in[17];
  const float* wv21 = (const float*)d_in[18];
  const float* bv21 = (const float*)d_in[19];
  const float* wv22 = (const float*)d_in[20];
  const float* bv22 = (const float*)d_in[21];
  const float* wo1  = (const float*)d_in[22];
  const float* bo1  = (const float*)d_in[23];
  const float* wo2  = (const float*)d_in[24];
  const float* bo2  = (const float*)d_in[25];

  float* ws   = (float*)d_ws;
  float* wt6  = ws + OFF_WT6;
  float* wot  = ws + OFF_WOT;
  float* weff = ws + OFF_WEFF;
  float* beff = ws + OFF_BEFF;
  uint16_t* Qb = (uint16_t*)(ws + OFF_QB);
  uint16_t* Kb = (uint16_t*)(ws + OFF_KB);
  uint16_t* Vt = (uint16_t*)(ws + OFF_VT);
  float* P2   = ws + OFF_P2;
  float* L2   = ws + OFF_L2;
  float* aot  = ws + OFF_AOT;
  float* out  = (float*)d_out;

  k_transpose<<<1216, 256, 0, stream>>>(wf1, wg1, wh1, wf2, wg2, wh2, wo1, wo2, wt6, wot);
  k_weff<<<130, 256, 0, stream>>>(wot, wv11, wv12, wv21, wv22,
                                  bv11, bv12, bv21, bv22, bo1, bo2, weff, beff);
  k_proj<<<768, 64, 0, stream>>>(x, y, wt6, bf1, bg1, bh1, bf2, bg2, bh2, Qb, Kb, Vt);
  k_attn2<<<2048, 64, 0, stream>>>(Qb, Kb, Vt, P2, L2);
  k_combine<<<128, 256, 0, stream>>>(P2, L2, aot);
  k_epi<<<4096, 64, 0, stream>>>(x, y, aot, weff, beff, out);
}

// Round 3
// 107.308 us; speedup vs baseline: 6.2613x; 1.2182x over previous
//
#include <hip/hip_runtime.h>
#include <hip/hip_bf16.h>
#include <cstdint>

#define N 4096
#define CC 256
#define CH 32
#define L2E 1.4426950408889634f

typedef __attribute__((ext_vector_type(8)))  short short8;
typedef __attribute__((ext_vector_type(16))) float f32x16;

// ---- workspace float offsets ----
#define OFF_WT6   0            // wt6   [6][256][32] fp32
#define OFF_WOT   49152        // wot   [2][512][256] fp32
#define OFF_WEFF  311296       // weff  [2][64][256] fp32
#define OFF_BEFF  344064       // beff  [2][256] fp32
#define OFF_QF    344576       // Qf [2][2][128 qt][2 half][64 lane][8] bf16 (scaled by log2e)
#define OFF_KF    606720       // Kf [2][2][128 kt][2 half][64 lane][8] bf16
#define OFF_VF    868864       // Vf [2][2][128 kt][2 fr  ][64 lane][8] bf16
#define OFF_AOT   1131008      // aot [8][32][4096] fp32   (ib = (ia*2+ik)*2+b)

__device__ __forceinline__ uint32_t cvtpk_bf16(float lo, float hi) {
  uint32_t r;
  asm("v_cvt_pk_bf16_f32 %0, %1, %2" : "=v"(r) : "v"(lo), "v"(hi));
  return r;
}

// ------------------------------------------------------------------
// 1) transpose small weight matrices
// ------------------------------------------------------------------
__global__ void k_transpose(const float* __restrict__ wf1, const float* __restrict__ wg1,
                            const float* __restrict__ wh1, const float* __restrict__ wf2,
                            const float* __restrict__ wg2, const float* __restrict__ wh2,
                            const float* __restrict__ wo1, const float* __restrict__ wo2,
                            float* __restrict__ wt6, float* __restrict__ wot) {
  int bid = blockIdx.x;
  if (bid < 192) {
    int idx = bid * 256 + threadIdx.x;                 // < 49152
    int ch = idx & 31, c = (idx >> 5) & 255, q = idx >> 13;
    const float* w = q == 0 ? wf1 : q == 1 ? wg1 : q == 2 ? wh1
                   : q == 3 ? wf2 : q == 4 ? wg2 : wh2;
    wt6[idx] = w[ch * CC + c];
  } else {
    int idx = (bid - 192) * 256 + threadIdx.x;         // < 262144
    int o = idx & 255, j = (idx >> 8) & 511, r = idx >> 17;
    const float* wo = r == 0 ? wo1 : wo2;
    wot[idx] = wo[o * 512 + j];
  }
}

// ------------------------------------------------------------------
// 2) effective epilogue weights: Weff = wo * [wv_a; wv_b], beff = bo + wo*bv
// ------------------------------------------------------------------
__global__ void k_weff(const float* __restrict__ wot,
                       const float* __restrict__ wv11, const float* __restrict__ wv12,
                       const float* __restrict__ wv21, const float* __restrict__ wv22,
                       const float* __restrict__ bv11, const float* __restrict__ bv12,
                       const float* __restrict__ bv21, const float* __restrict__ bv22,
                       const float* __restrict__ bo1, const float* __restrict__ bo2,
                       float* __restrict__ weff, float* __restrict__ beff) {
  int bid = blockIdx.x;
  int o = threadIdx.x;
  if (bid < 128) {
    int r = bid >> 6, ch = bid & 63, half = ch >> 5, chp = ch & 31;
    const float* wv = (r == 0) ? (half ? wv12 : wv11) : (half ? wv22 : wv21);
    const float* wocol = wot + ((size_t)r * 512 + half * 256) * 256 + o;
    float a = 0.f;
    for (int c = 0; c < 256; ++c)
      a = fmaf(wocol[(size_t)c * 256], wv[c * CH + chp], a);
    weff[((size_t)r * 64 + ch) * 256 + o] = a;
  } else {
    int r = bid - 128;
    const float* bo  = r == 0 ? bo1 : bo2;
    const float* bva = r == 0 ? bv11 : bv21;
    const float* bvb = r == 0 ? bv12 : bv22;
    const float* wocol = wot + (size_t)r * 512 * 256 + o;
    float a = bo[o];
    for (int c = 0; c < 256; ++c) {
      a = fmaf(wocol[(size_t)c * 256], bva[c], a);
      a = fmaf(wocol[(size_t)(c + 256) * 256], bvb[c], a);
    }
    beff[r * 256 + o] = a;
  }
}

// ------------------------------------------------------------------
// 3) projections -> bf16 MFMA-fragment layout in global memory.
//    Block: 256 thr = 4 waves; lane l = n-offset, wave w = c-range (64 c each).
//    LDS combine, wave 0 stores fragments.
//    Q/K frag elem (half, lane, j) = X[row = lane&31][c = half*16 + (lane>>5)*8 + j]
//    V   frag elem (fr,   lane, j) = V[key = fr*16 + (lane>>5)*8 + j][ch = lane&31]
// ------------------------------------------------------------------
__global__ __launch_bounds__(256) void k_proj(
    const float* __restrict__ x, const float* __restrict__ y,
    const float* __restrict__ wt6,
    const float* __restrict__ bf1, const float* __restrict__ bg1, const float* __restrict__ bh1,
    const float* __restrict__ bf2, const float* __restrict__ bg2, const float* __restrict__ bh2,
    uint16_t* __restrict__ Qf, uint16_t* __restrict__ Kf, uint16_t* __restrict__ Vf) {
  __shared__ float red[3][32][64];
  int nt = blockIdx.x & 63;
  int bq = blockIdx.x >> 6;
  int q = bq % 6, b = bq / 6;
  int l = threadIdx.x & 63, w = threadIdx.x >> 6;
  const float* src = (q == 3 || q == 4) ? y : x;     // f2,g2 from y; h1,h2 from x
  src += (size_t)b * CC * N + nt * 64 + l;
  const float* wt = wt6 + (size_t)q * CC * CH;
  float acc[CH];
#pragma unroll
  for (int ch = 0; ch < CH; ++ch) acc[ch] = 0.f;
#pragma unroll 4
  for (int ci = 0; ci < 64; ++ci) {
    int c = w * 64 + ci;
    float xv = src[(size_t)c * N];
    const float* wr = wt + c * CH;
#pragma unroll
    for (int ch = 0; ch < CH; ++ch) acc[ch] = fmaf(wr[ch], xv, acc[ch]);
  }
  if (w > 0) {
#pragma unroll
    for (int ch = 0; ch < CH; ++ch) red[w - 1][ch][l] = acc[ch];
  }
  __syncthreads();
  if (w != 0) return;
#pragma unroll
  for (int ww = 0; ww < 3; ++ww)
#pragma unroll
    for (int ch = 0; ch < CH; ++ch) acc[ch] += red[ww][ch][l];

  const float* bias = q == 0 ? bf1 : q == 1 ? bg1 : q == 2 ? bh1
                    : q == 3 ? bf2 : q == 4 ? bg2 : bh2;
  bool isf = (q == 0 || q == 3);
  float v[CH];
#pragma unroll
  for (int ch = 0; ch < CH; ++ch) {
    float t = acc[ch] + bias[ch];
    v[ch] = isf ? t * L2E : t;
  }
  int n = nt * 64 + l;
  int tile = n >> 5, r = n & 31;
  int inst = (q >= 3) ? 1 : 0;
  int b128 = (inst * 2 + b) * 128 + tile;
  if (q == 2 || q == 5) {
    // V fragment: scattered ushort stores (8-lane contiguous groups)
    uint16_t* outp = Vf + (size_t)b128 * 1024;
    int fr = r >> 4, l5k = (r >> 3) & 1, jn = r & 7;
    uint16_t* bp = outp + fr * 512 + l5k * 256 + jn;
#pragma unroll
    for (int ch = 0; ch < CH; ++ch) {
      uint32_t pk = cvtpk_bf16(v[ch], v[ch]);
      bp[ch * 8] = (uint16_t)pk;
    }
  } else {
    // Q/K fragment: 16 aligned u32 stores (c-pairs adjacent)
    uint32_t* outp = (uint32_t*)((q == 0 || q == 3) ? Qf : Kf) + (size_t)b128 * 512;
#pragma unroll
    for (int c = 0; c < CH; c += 2) {
      uint32_t pk = cvtpk_bf16(v[c], v[c + 1]);
      int half = c >> 4, l5c = (c >> 3) & 1, jh = (c & 7) >> 1;
      outp[half * 256 + l5c * 128 + r * 4 + jh] = pk;
    }
  }
}

// ------------------------------------------------------------------
// 4) MFMA flash attention. Block = 512 thr (8 waves) = one 32-query tile
//    of one (instance, batch). Wave w owns keys [w*512, w*512+512).
//    All loads are frag-layout: base + lane*16B, fully coalesced.
//    S^T = mfma(K, Q): lane holds P[q=lane&31][16 keys]; exp2 raw (no shift);
//    P->bf16 A-frags via cvt_pk + permlane32_swap; AO += mfma(P, Vfrag).
//    LDS reduce across waves, normalized transposed write to aot[ib][ch][q].
// ------------------------------------------------------------------
__global__ __launch_bounds__(512) void k_attn3(const uint16_t* __restrict__ Qf,
                                               const uint16_t* __restrict__ Kf,
                                               const uint16_t* __restrict__ Vf,
                                               float* __restrict__ aot) {
  __shared__ float redAO[8][32][33];
  __shared__ float redL[8][32];
  int bid = blockIdx.x;
  int qt = bid & 127, b = (bid >> 7) & 1, i = bid >> 8;
  int ia = i >> 1, ik = i & 1;
  int tid = threadIdx.x, w = tid >> 6, l = tid & 63, l31 = l & 31, l5 = l >> 5;

  const uint16_t* Qp = Qf + (size_t)((ia * 2 + b) * 128 + qt) * 1024 + l * 8;
  const uint16_t* Kp = Kf + (size_t)((ik * 2 + b) * 128 + w * 16) * 1024 + l * 8;
  const uint16_t* Vp = Vf + (size_t)((ik * 2 + b) * 128 + w * 16) * 1024 + l * 8;

  short8 bq0 = *(const short8*)(Qp);
  short8 bq1 = *(const short8*)(Qp + 512);

  f32x16 zero16, ao;
#pragma unroll
  for (int r = 0; r < 16; ++r) { zero16[r] = 0.f; ao[r] = 0.f; }
  float lacc = 0.f;

  for (int t = 0; t < 16; ++t) {
    const uint16_t* kt = Kp + t * 1024;
    short8 ak0 = *(const short8*)(kt);
    short8 ak1 = *(const short8*)(kt + 512);
    const uint16_t* vt = Vp + t * 1024;
    short8 bv0 = *(const short8*)(vt);
    short8 bv1 = *(const short8*)(vt + 512);

    f32x16 sa = __builtin_amdgcn_mfma_f32_32x32x16_bf16(ak0, bq0, zero16, 0, 0, 0);
    sa = __builtin_amdgcn_mfma_f32_32x32x16_bf16(ak1, bq1, sa, 0, 0, 0);

    float p[16];
#pragma unroll
    for (int r = 0; r < 16; ++r) p[r] = __builtin_amdgcn_exp2f(sa[r]);

    float t0 = 0.f, t1 = 0.f;
#pragma unroll
    for (int r = 0; r < 8; ++r) { t0 += p[2 * r]; t1 += p[2 * r + 1]; }
    lacc += t0 + t1;

    uint32_t wreg[8];
#pragma unroll
    for (int kh = 0; kh < 2; ++kh) {
      int base = kh * 8;
      uint32_t x0 = cvtpk_bf16(p[base + 0], p[base + 1]);
      uint32_t y0 = cvtpk_bf16(p[base + 4], p[base + 5]);
      asm volatile("v_permlane32_swap_b32 %0, %1" : "+v"(x0), "+v"(y0));
      uint32_t x1 = cvtpk_bf16(p[base + 2], p[base + 3]);
      uint32_t y1 = cvtpk_bf16(p[base + 6], p[base + 7]);
      asm volatile("v_permlane32_swap_b32 %0, %1" : "+v"(x1), "+v"(y1));
      wreg[kh * 4 + 0] = x0; wreg[kh * 4 + 1] = x1; wreg[kh * 4 + 2] = y0; wreg[kh * 4 + 3] = y1;
    }
    short8 pa0, pa1;
    {
      typedef __attribute__((ext_vector_type(4))) uint32_t u32x4;
      u32x4 u0 = {wreg[0], wreg[1], wreg[2], wreg[3]};
      u32x4 u1 = {wreg[4], wreg[5], wreg[6], wreg[7]};
      pa0 = __builtin_bit_cast(short8, u0);
      pa1 = __builtin_bit_cast(short8, u1);
    }
    ao = __builtin_amdgcn_mfma_f32_32x32x16_bf16(pa0, bv0, ao, 0, 0, 0);
    ao = __builtin_amdgcn_mfma_f32_32x32x16_bf16(pa1, bv1, ao, 0, 0, 0);
  }

  // per-wave partials -> LDS
#pragma unroll
  for (int r = 0; r < 16; ++r) {
    int row = (r & 3) + 8 * (r >> 2) + 4 * l5;       // query within tile
    redAO[w][row][l31] = ao[r];
  }
  lacc += __shfl_xor(lacc, 32);
  if (l < 32) redL[w][l31] = lacc;
  __syncthreads();

  // combine + normalize + transposed write (each thread: q=tid&31, 2 channels)
  int q5 = tid & 31, chb = tid >> 5;                 // chb in [0,16)
  float lsum = 0.f;
#pragma unroll
  for (int ww = 0; ww < 8; ++ww) lsum += redL[ww][q5];
  float inv = __builtin_amdgcn_rcpf(lsum);
  float s0 = 0.f, s1 = 0.f;
#pragma unroll
  for (int ww = 0; ww < 8; ++ww) {
    s0 += redAO[ww][q5][chb];
    s1 += redAO[ww][q5][chb + 16];
  }
  int ib = i * 2 + b;
  float* ob = aot + (size_t)ib * CH * N + qt * 32 + q5;
  ob[(size_t)chb * N] = s0 * inv;
  ob[(size_t)(chb + 16) * N] = s1 * inv;
}

// ------------------------------------------------------------------
// 5) epilogue: out[r][b][o][m] = src + Weff * AO_cat + beff
// ------------------------------------------------------------------
__global__ __launch_bounds__(64) void k_epi(const float* __restrict__ x, const float* __restrict__ y,
                                            const float* __restrict__ aot,
                                            const float* __restrict__ weff,
                                            const float* __restrict__ beff,
                                            float* __restrict__ out) {
  int bid = blockIdx.x;
  int mt = bid & 63, og = (bid >> 6) & 15, b = (bid >> 10) & 1, r = bid >> 11;
  int m = mt * 64 + threadIdx.x;
  int o0 = og * 16;
  const float* src = r == 0 ? x : y;
  const float* A0 = aot + (size_t)(r * 4 + b) * CH * N;        // instance (r, ik=0)
  const float* A1 = aot + (size_t)(r * 4 + 2 + b) * CH * N;    // instance (r, ik=1)
  const float* wrow = weff + (size_t)r * 64 * 256;
  float acc[16];
#pragma unroll
  for (int j = 0; j < 16; ++j) acc[j] = 0.f;
#pragma unroll 4
  for (int ch = 0; ch < 32; ++ch) {
    float av = A0[(size_t)ch * N + m];
    const float* wr = wrow + ch * 256 + o0;
#pragma unroll
    for (int j = 0; j < 16; ++j) acc[j] = fmaf(wr[j], av, acc[j]);
  }
#pragma unroll 4
  for (int ch = 0; ch < 32; ++ch) {
    float av = A1[(size_t)ch * N + m];
    const float* wr = wrow + (32 + ch) * 256 + o0;
#pragma unroll
    for (int j = 0; j < 16; ++j) acc[j] = fmaf(wr[j], av, acc[j]);
  }
  float* outr = out + (size_t)r * 2 * CC * N;
#pragma unroll
  for (int j = 0; j < 16; ++j) {
    int o = o0 + j;
    size_t off = ((size_t)b * CC + o) * N + m;
    outr[off] = src[off] + acc[j] + beff[r * CC + o];
  }
}

extern "C" void kernel_launch(void* const* d_in, const int* in_sizes, int n_in,
                              void* d_out, int out_size, void* d_ws, size_t ws_size,
                              hipStream_t stream) {
  const float* x    = (const float*)d_in[0];
  const float* y    = (const float*)d_in[1];
  const float* wf1  = (const float*)d_in[2];
  const float* bf1  = (const float*)d_in[3];
  const float* wg1  = (const float*)d_in[4];
  const float* bg1  = (const float*)d_in[5];
  const float* wh1  = (const float*)d_in[6];
  const float* bh1  = (const float*)d_in[7];
  const float* wf2  = (const float*)d_in[8];
  const float* bf2  = (const float*)d_in[9];
  const float* wg2  = (const float*)d_in[10];
  const float* bg2  = (const float*)d_in[11];
  const float* wh2  = (const float*)d_in[12];
  const float* bh2  = (const float*)d_in[13];
  const float* wv11 = (const float*)d_in[14];
  const float* bv11 = (const float*)d_in[15];
  const float* wv12 = (const float*)d_in[16];
  const float* bv12 = (const float*)d_in[17];
  const float* wv21 = (const float*)d_in[18];
  const float* bv21 = (const float*)d_in[19];
  const float* wv22 = (const float*)d_in[20];
  const float* bv22 = (const float*)d_in[21];
  const float* wo1  = (const float*)d_in[22];
  const float* bo1  = (const float*)d_in[23];
  const float* wo2  = (const float*)d_in[24];
  const float* bo2  = (const float*)d_in[25];

  float* ws   = (float*)d_ws;
  float* wt6  = ws + OFF_WT6;
  float* wot  = ws + OFF_WOT;
  float* weff = ws + OFF_WEFF;
  float* beff = ws + OFF_BEFF;
  uint16_t* Qf = (uint16_t*)(ws + OFF_QF);
  uint16_t* Kf = (uint16_t*)(ws + OFF_KF);
  uint16_t* Vf = (uint16_t*)(ws + OFF_VF);
  float* aot  = ws + OFF_AOT;
  float* out  = (float*)d_out;

  k_transpose<<<1216, 256, 0, stream>>>(wf1, wg1, wh1, wf2, wg2, wh2, wo1, wo2, wt6, wot);
  k_weff<<<130, 256, 0, stream>>>(wot, wv11, wv12, wv21, wv22,
                                  bv11, bv12, bv21, bv22, bo1, bo2, weff, beff);
  k_proj<<<768, 256, 0, stream>>>(x, y, wt6, bf1, bg1, bh1, bf2, bg2, bh2, Qf, Kf, Vf);
  k_attn3<<<1024, 512, 0, stream>>>(Qf, Kf, Vf, aot);
  k_epi<<<4096, 64, 0, stream>>>(x, y, aot, weff, beff, out);
}

// Round 4
// 79.576 us; speedup vs baseline: 8.4432x; 1.3485x over previous
//
#include <hip/hip_runtime.h>
#include <hip/hip_bf16.h>
#include <cstdint>

#define N 4096
#define CC 256
#define CH 32
#define L2E 1.4426950408889634f

typedef __attribute__((ext_vector_type(8)))  short short8;
typedef __attribute__((ext_vector_type(16))) float f32x16;
typedef __attribute__((ext_vector_type(4)))  uint32_t u32x4;
typedef __attribute__((ext_vector_type(2)))  uint32_t u32x2;

// ---- workspace float offsets ----
#define OFF_WT6   0            // wt6   [6][256][32] fp32
#define OFF_WOT   49152        // wot   [2][512][256] fp32
#define OFF_WEFF  311296       // weff  [2][64][256] fp32
#define OFF_BEFF  344064       // beff  [2][256] fp32
#define OFF_QF    344576       // Qf [2][2][128 qt][2 half][64 lane][8] bf16 (scaled by log2e)
#define OFF_KF    606720       // Kf [2][2][128 kt][2 half][64 lane][8] bf16
#define OFF_VF    868864       // Vf [2][2][128 kt][2 fr  ][64 lane][8] bf16
#define OFF_AOT   1131008      // aot [8][32][4096] fp32   (ib = (ia*2+ik)*2+b)

__device__ __forceinline__ uint32_t cvtpk_bf16(float lo, float hi) {
  uint32_t r;
  asm("v_cvt_pk_bf16_f32 %0, %1, %2" : "=v"(r) : "v"(lo), "v"(hi));
  return r;
}

// ------------------------------------------------------------------
// 1) transpose small weight matrices
// ------------------------------------------------------------------
__global__ void k_transpose(const float* __restrict__ wf1, const float* __restrict__ wg1,
                            const float* __restrict__ wh1, const float* __restrict__ wf2,
                            const float* __restrict__ wg2, const float* __restrict__ wh2,
                            const float* __restrict__ wo1, const float* __restrict__ wo2,
                            float* __restrict__ wt6, float* __restrict__ wot) {
  int bid = blockIdx.x;
  if (bid < 192) {
    int idx = bid * 256 + threadIdx.x;                 // < 49152
    int ch = idx & 31, c = (idx >> 5) & 255, q = idx >> 13;
    const float* w = q == 0 ? wf1 : q == 1 ? wg1 : q == 2 ? wh1
                   : q == 3 ? wf2 : q == 4 ? wg2 : wh2;
    wt6[idx] = w[ch * CC + c];
  } else {
    int idx = (bid - 192) * 256 + threadIdx.x;         // < 262144
    int o = idx & 255, j = (idx >> 8) & 511, r = idx >> 17;
    const float* wo = r == 0 ? wo1 : wo2;
    wot[idx] = wo[o * 512 + j];
  }
}

// ------------------------------------------------------------------
// 2) effective epilogue weights: Weff = wo * [wv_a; wv_b], beff = bo + wo*bv
// ------------------------------------------------------------------
__global__ void k_weff(const float* __restrict__ wot,
                       const float* __restrict__ wv11, const float* __restrict__ wv12,
                       const float* __restrict__ wv21, const float* __restrict__ wv22,
                       const float* __restrict__ bv11, const float* __restrict__ bv12,
                       const float* __restrict__ bv21, const float* __restrict__ bv22,
                       const float* __restrict__ bo1, const float* __restrict__ bo2,
                       float* __restrict__ weff, float* __restrict__ beff) {
  int bid = blockIdx.x;
  int o = threadIdx.x;
  if (bid < 128) {
    int r = bid >> 6, ch = bid & 63, half = ch >> 5, chp = ch & 31;
    const float* wv = (r == 0) ? (half ? wv12 : wv11) : (half ? wv22 : wv21);
    const float* wocol = wot + ((size_t)r * 512 + half * 256) * 256 + o;
    float a = 0.f;
    for (int c = 0; c < 256; ++c)
      a = fmaf(wocol[(size_t)c * 256], wv[c * CH + chp], a);
    weff[((size_t)r * 64 + ch) * 256 + o] = a;
  } else {
    int r = bid - 128;
    const float* bo  = r == 0 ? bo1 : bo2;
    const float* bva = r == 0 ? bv11 : bv21;
    const float* bvb = r == 0 ? bv12 : bv22;
    const float* wocol = wot + (size_t)r * 512 * 256 + o;
    float a = bo[o];
    for (int c = 0; c < 256; ++c) {
      a = fmaf(wocol[(size_t)c * 256], bva[c], a);
      a = fmaf(wocol[(size_t)(c + 256) * 256], bvb[c], a);
    }
    beff[r * 256 + o] = a;
  }
}

// ------------------------------------------------------------------
// 3) fused projections v2. Grid: 256 blocks = (src 2) x (b 2) x (nt 64),
//    block = 1024 thr (16 waves). Stage src tile [256 c][64 n] fp32 into
//    LDS once (coalesced float4), then waves compute (q, ch-slice) dots
//    reading LDS (bank-conflict-free) with wave-uniform scalar weights.
//    x-blocks: f1,g1,h1,h2 (wave = q*4 slices of 8ch); y-blocks: f2,g2
//    (wave = q*8 slices of 4ch). Outputs in MFMA fragment layouts:
//    Q/K frag elem (half, lane, j) = X[row = lane&31][c = half*16 + (lane>>5)*8 + j]
//    V   frag elem (fr,   lane, j) = V[key = fr*16 + (lane>>5)*8 + j][ch = lane&31]
// ------------------------------------------------------------------
__global__ __launch_bounds__(1024) void k_proj(
    const float* __restrict__ x, const float* __restrict__ y,
    const float* __restrict__ wt6,
    const float* __restrict__ bf1, const float* __restrict__ bg1, const float* __restrict__ bh1,
    const float* __restrict__ bf2, const float* __restrict__ bg2, const float* __restrict__ bh2,
    uint16_t* __restrict__ Qf, uint16_t* __restrict__ Kf, uint16_t* __restrict__ Vf) {
  __shared__ float xl[256 * 64];                     // 64 KB
  int bid = blockIdx.x;
  int nt = bid & 63, b = (bid >> 6) & 1, sy = bid >> 7;
  int tid = threadIdx.x, lane = tid & 63;
  int w = __builtin_amdgcn_readfirstlane(tid >> 6);

  const float* src = (sy ? y : x) + (size_t)b * CC * N + nt * 64;
#pragma unroll
  for (int rnd = 0; rnd < 4; ++rnd) {
    int u = rnd * 1024 + tid;                        // 16B units; c = u>>4, np = u&15
    *(float4*)&xl[u * 4] = *(const float4*)(src + (size_t)(u >> 4) * N + (u & 15) * 4);
  }
  __syncthreads();

  int tile = nt * 2 + (lane >> 5), r = lane & 31;

  if (!sy) {
    // ---- x-block: ql 0=f1 1=g1 2=h1 3=h2 ----
    int ql = w >> 2, chq = w & 3, ch0 = chq * 8;
    int q = (ql == 3) ? 5 : ql;
    const float* wp = wt6 + (size_t)q * CC * CH + ch0;
    float acc[8];
#pragma unroll
    for (int j = 0; j < 8; ++j) acc[j] = 0.f;
#pragma unroll 4
    for (int c = 0; c < 256; ++c) {
      float xv = xl[c * 64 + lane];
#pragma unroll
      for (int j = 0; j < 8; ++j) acc[j] = fmaf(wp[c * 32 + j], xv, acc[j]);
    }
    const float* bias = ql == 0 ? bf1 : ql == 1 ? bg1 : ql == 2 ? bh1 : bh2;
    float vv[8];
#pragma unroll
    for (int j = 0; j < 8; ++j) {
      float t = acc[j] + bias[ch0 + j];
      vv[j] = (ql == 0) ? t * L2E : t;
    }
    if (ql < 2) {
      // f1 -> Qf inst0, g1 -> Kf inst0: one dwordx4 store
      uint32_t* dst = (uint32_t*)(ql == 0 ? Qf : Kf)
                    + ((size_t)(b * 128 + tile)) * 512
                    + (chq >> 1) * 256 + (chq & 1) * 128 + r * 4;
      u32x4 pk;
#pragma unroll
      for (int t = 0; t < 4; ++t) pk[t] = cvtpk_bf16(vv[2 * t], vv[2 * t + 1]);
      *(u32x4*)dst = pk;
    } else {
      // h1 -> Vf inst0, h2 -> Vf inst1: scattered ushort stores
      int inst = ql - 2;
      uint16_t* bp = Vf + ((size_t)((inst * 2 + b) * 128 + tile)) * 1024
                   + (r >> 4) * 512 + ((r >> 3) & 1) * 256 + (r & 7);
#pragma unroll
      for (int j = 0; j < 8; ++j)
        bp[(ch0 + j) * 8] = (uint16_t)cvtpk_bf16(vv[j], vv[j]);
    }
  } else {
    // ---- y-block: ql 0=f2 1=g2 ----
    int ql = w >> 3, cho = w & 7, ch0 = cho * 4;
    int q = 3 + ql;
    const float* wp = wt6 + (size_t)q * CC * CH + ch0;
    float acc[4];
#pragma unroll
    for (int j = 0; j < 4; ++j) acc[j] = 0.f;
#pragma unroll 4
    for (int c = 0; c < 256; ++c) {
      float xv = xl[c * 64 + lane];
#pragma unroll
      for (int j = 0; j < 4; ++j) acc[j] = fmaf(wp[c * 32 + j], xv, acc[j]);
    }
    const float* bias = ql == 0 ? bf2 : bg2;
    float vv[4];
#pragma unroll
    for (int j = 0; j < 4; ++j) {
      float t = acc[j] + bias[ch0 + j];
      vv[j] = (ql == 0) ? t * L2E : t;
    }
    // f2 -> Qf inst1, g2 -> Kf inst1: one dwordx2 store
    int half = ch0 >> 4, l5c = (ch0 >> 3) & 1, jh0 = (ch0 & 7) >> 1;
    uint32_t* dst = (uint32_t*)(ql == 0 ? Qf : Kf)
                  + ((size_t)((2 + b) * 128 + tile)) * 512
                  + half * 256 + l5c * 128 + r * 4 + jh0;
    u32x2 pk;
    pk[0] = cvtpk_bf16(vv[0], vv[1]);
    pk[1] = cvtpk_bf16(vv[2], vv[3]);
    *(u32x2*)dst = pk;
  }
}

// ------------------------------------------------------------------
// 4) MFMA flash attention. Block = 512 thr (8 waves) = one 32-query tile
//    of one (instance, batch). Wave w owns keys [w*512, w*512+512).
//    All loads are frag-layout: base + lane*16B, fully coalesced.
// ------------------------------------------------------------------
__global__ __launch_bounds__(512) void k_attn3(const uint16_t* __restrict__ Qf,
                                               const uint16_t* __restrict__ Kf,
                                               const uint16_t* __restrict__ Vf,
                                               float* __restrict__ aot) {
  __shared__ float redAO[8][32][33];
  __shared__ float redL[8][32];
  int bid = blockIdx.x;
  int qt = bid & 127, b = (bid >> 7) & 1, i = bid >> 8;
  int ia = i >> 1, ik = i & 1;
  int tid = threadIdx.x, w = tid >> 6, l = tid & 63, l31 = l & 31, l5 = l >> 5;

  const uint16_t* Qp = Qf + (size_t)((ia * 2 + b) * 128 + qt) * 1024 + l * 8;
  const uint16_t* Kp = Kf + (size_t)((ik * 2 + b) * 128 + w * 16) * 1024 + l * 8;
  const uint16_t* Vp = Vf + (size_t)((ik * 2 + b) * 128 + w * 16) * 1024 + l * 8;

  short8 bq0 = *(const short8*)(Qp);
  short8 bq1 = *(const short8*)(Qp + 512);

  f32x16 zero16, ao;
#pragma unroll
  for (int r = 0; r < 16; ++r) { zero16[r] = 0.f; ao[r] = 0.f; }
  float lacc = 0.f;

  for (int t = 0; t < 16; ++t) {
    const uint16_t* kt = Kp + t * 1024;
    short8 ak0 = *(const short8*)(kt);
    short8 ak1 = *(const short8*)(kt + 512);
    const uint16_t* vt = Vp + t * 1024;
    short8 bv0 = *(const short8*)(vt);
    short8 bv1 = *(const short8*)(vt + 512);

    f32x16 sa = __builtin_amdgcn_mfma_f32_32x32x16_bf16(ak0, bq0, zero16, 0, 0, 0);
    sa = __builtin_amdgcn_mfma_f32_32x32x16_bf16(ak1, bq1, sa, 0, 0, 0);

    float p[16];
#pragma unroll
    for (int r = 0; r < 16; ++r) p[r] = __builtin_amdgcn_exp2f(sa[r]);

    float t0 = 0.f, t1 = 0.f;
#pragma unroll
    for (int r = 0; r < 8; ++r) { t0 += p[2 * r]; t1 += p[2 * r + 1]; }
    lacc += t0 + t1;

    uint32_t wreg[8];
#pragma unroll
    for (int kh = 0; kh < 2; ++kh) {
      int base = kh * 8;
      uint32_t x0 = cvtpk_bf16(p[base + 0], p[base + 1]);
      uint32_t y0 = cvtpk_bf16(p[base + 4], p[base + 5]);
      asm volatile("v_permlane32_swap_b32 %0, %1" : "+v"(x0), "+v"(y0));
      uint32_t x1 = cvtpk_bf16(p[base + 2], p[base + 3]);
      uint32_t y1 = cvtpk_bf16(p[base + 6], p[base + 7]);
      asm volatile("v_permlane32_swap_b32 %0, %1" : "+v"(x1), "+v"(y1));
      wreg[kh * 4 + 0] = x0; wreg[kh * 4 + 1] = x1; wreg[kh * 4 + 2] = y0; wreg[kh * 4 + 3] = y1;
    }
    short8 pa0, pa1;
    {
      u32x4 u0 = {wreg[0], wreg[1], wreg[2], wreg[3]};
      u32x4 u1 = {wreg[4], wreg[5], wreg[6], wreg[7]};
      pa0 = __builtin_bit_cast(short8, u0);
      pa1 = __builtin_bit_cast(short8, u1);
    }
    ao = __builtin_amdgcn_mfma_f32_32x32x16_bf16(pa0, bv0, ao, 0, 0, 0);
    ao = __builtin_amdgcn_mfma_f32_32x32x16_bf16(pa1, bv1, ao, 0, 0, 0);
  }

  // per-wave partials -> LDS
#pragma unroll
  for (int r = 0; r < 16; ++r) {
    int row = (r & 3) + 8 * (r >> 2) + 4 * l5;       // query within tile
    redAO[w][row][l31] = ao[r];
  }
  lacc += __shfl_xor(lacc, 32);
  if (l < 32) redL[w][l31] = lacc;
  __syncthreads();

  // combine + normalize + transposed write (each thread: q=tid&31, 2 channels)
  int q5 = tid & 31, chb = tid >> 5;                 // chb in [0,16)
  float lsum = 0.f;
#pragma unroll
  for (int ww = 0; ww < 8; ++ww) lsum += redL[ww][q5];
  float inv = __builtin_amdgcn_rcpf(lsum);
  float s0 = 0.f, s1 = 0.f;
#pragma unroll
  for (int ww = 0; ww < 8; ++ww) {
    s0 += redAO[ww][q5][chb];
    s1 += redAO[ww][q5][chb + 16];
  }
  int ib = i * 2 + b;
  float* ob = aot + (size_t)ib * CH * N + qt * 32 + q5;
  ob[(size_t)chb * N] = s0 * inv;
  ob[(size_t)(chb + 16) * N] = s1 * inv;
}

// ------------------------------------------------------------------
// 5) epilogue: out[r][b][o][m] = src + Weff * AO_cat + beff
// ------------------------------------------------------------------
__global__ __launch_bounds__(64) void k_epi(const float* __restrict__ x, const float* __restrict__ y,
                                            const float* __restrict__ aot,
                                            const float* __restrict__ weff,
                                            const float* __restrict__ beff,
                                            float* __restrict__ out) {
  int bid = blockIdx.x;
  int mt = bid & 63, og = (bid >> 6) & 15, b = (bid >> 10) & 1, r = bid >> 11;
  int m = mt * 64 + threadIdx.x;
  int o0 = og * 16;
  const float* src = r == 0 ? x : y;
  const float* A0 = aot + (size_t)(r * 4 + b) * CH * N;        // instance (r, ik=0)
  const float* A1 = aot + (size_t)(r * 4 + 2 + b) * CH * N;    // instance (r, ik=1)
  const float* wrow = weff + (size_t)r * 64 * 256;
  float acc[16];
#pragma unroll
  for (int j = 0; j < 16; ++j) acc[j] = 0.f;
#pragma unroll 4
  for (int ch = 0; ch < 32; ++ch) {
    float av = A0[(size_t)ch * N + m];
    const float* wr = wrow + ch * 256 + o0;
#pragma unroll
    for (int j = 0; j < 16; ++j) acc[j] = fmaf(wr[j], av, acc[j]);
  }
#pragma unroll 4
  for (int ch = 0; ch < 32; ++ch) {
    float av = A1[(size_t)ch * N + m];
    const float* wr = wrow + (32 + ch) * 256 + o0;
#pragma unroll
    for (int j = 0; j < 16; ++j) acc[j] = fmaf(wr[j], av, acc[j]);
  }
  float* outr = out + (size_t)r * 2 * CC * N;
#pragma unroll
  for (int j = 0; j < 16; ++j) {
    int o = o0 + j;
    size_t off = ((size_t)b * CC + o) * N + m;
    outr[off] = src[off] + acc[j] + beff[r * CC + o];
  }
}

extern "C" void kernel_launch(void* const* d_in, const int* in_sizes, int n_in,
                              void* d_out, int out_size, void* d_ws, size_t ws_size,
                              hipStream_t stream) {
  const float* x    = (const float*)d_in[0];
  const float* y    = (const float*)d_in[1];
  const float* wf1  = (const float*)d_in[2];
  const float* bf1  = (const float*)d_in[3];
  const float* wg1  = (const float*)d_in[4];
  const float* bg1  = (const float*)d_in[5];
  const float* wh1  = (const float*)d_in[6];
  const float* bh1  = (const float*)d_in[7];
  const float* wf2  = (const float*)d_in[8];
  const float* bf2  = (const float*)d_in[9];
  const float* wg2  = (const float*)d_in[10];
  const float* bg2  = (const float*)d_in[11];
  const float* wh2  = (const float*)d_in[12];
  const float* bh2  = (const float*)d_in[13];
  const float* wv11 = (const float*)d_in[14];
  const float* bv11 = (const float*)d_in[15];
  const float* wv12 = (const float*)d_in[16];
  const float* bv12 = (const float*)d_in[17];
  const float* wv21 = (const float*)d_in[18];
  const float* bv21 = (const float*)d_in[19];
  const float* wv22 = (const float*)d_in[20];
  const float* bv22 = (const float*)d_in[21];
  const float* wo1  = (const float*)d_in[22];
  const float* bo1  = (const float*)d_in[23];
  const float* wo2  = (const float*)d_in[24];
  const float* bo2  = (const float*)d_in[25];

  float* ws   = (float*)d_ws;
  float* wt6  = ws + OFF_WT6;
  float* wot  = ws + OFF_WOT;
  float* weff = ws + OFF_WEFF;
  float* beff = ws + OFF_BEFF;
  uint16_t* Qf = (uint16_t*)(ws + OFF_QF);
  uint16_t* Kf = (uint16_t*)(ws + OFF_KF);
  uint16_t* Vf = (uint16_t*)(ws + OFF_VF);
  float* aot  = ws + OFF_AOT;
  float* out  = (float*)d_out;

  k_transpose<<<1216, 256, 0, stream>>>(wf1, wg1, wh1, wf2, wg2, wh2, wo1, wo2, wt6, wot);
  k_weff<<<130, 256, 0, stream>>>(wot, wv11, wv12, wv21, wv22,
                                  bv11, bv12, bv21, bv22, bo1, bo2, weff, beff);
  k_proj<<<256, 1024, 0, stream>>>(x, y, wt6, bf1, bg1, bh1, bf2, bg2, bh2, Qf, Kf, Vf);
  k_attn3<<<1024, 512, 0, stream>>>(Qf, Kf, Vf, aot);
  k_epi<<<4096, 64, 0, stream>>>(x, y, aot, weff, beff, out);
}

// Round 6
// 77.685 us; speedup vs baseline: 8.6489x; 1.0244x over previous
//
#include <hip/hip_runtime.h>
#include <hip/hip_bf16.h>
#include <cstdint>

#define N 4096
#define CC 256
#define CH 32
#define L2E 1.4426950408889634f

typedef __attribute__((ext_vector_type(8)))  short short8;
typedef __attribute__((ext_vector_type(16))) float f32x16;
typedef __attribute__((ext_vector_type(4)))  uint32_t u32x4;

// ---- workspace float offsets ----
#define OFF_WFRAG 0            // wfragb [6][16 kb][64 lane][8 j] bf16 (as u16)
#define OFF_WOT   49152        // wot   [2][512][256] fp32
#define OFF_WEFF  311296       // weff  [2][64][256] fp32
#define OFF_BEFF  344064       // beff  [2][256] fp32
#define OFF_QF    344576       // Qf [2][2][128 nt][2 half][64 lane][8] bf16 (scaled by log2e)
#define OFF_KF    606720       // Kf [2][2][128 nt][2 half][64 lane][8] bf16
#define OFF_VF    868864       // Vf [2][2][128 nt][2 fr  ][64 lane][8] bf16
#define OFF_AOT   1131008      // aot [8][32][4096] fp32   (ib = (ia*2+ik)*2+b)

__device__ __forceinline__ uint32_t cvtpk_bf16(float lo, float hi) {
  uint32_t r;
  asm("v_cvt_pk_bf16_f32 %0, %1, %2" : "=v"(r) : "v"(lo), "v"(hi));
  return r;
}

// D-layout rows (16 regs, row=(r&3)+8*(r>>2)+4*l5, col=l31) -> two bf16 frags
// (lane l31 = col, slots l5*8+j = rows 0..15 / 16..31). Verbatim from validated attn.
__device__ __forceinline__ void rows_to_frags(const float* p, u32x4& lo, u32x4& hi) {
#pragma unroll
  for (int kh = 0; kh < 2; ++kh) {
    int base = kh * 8;
    uint32_t x0 = cvtpk_bf16(p[base + 0], p[base + 1]);
    uint32_t y0 = cvtpk_bf16(p[base + 4], p[base + 5]);
    asm volatile("v_permlane32_swap_b32 %0, %1" : "+v"(x0), "+v"(y0));
    uint32_t x1 = cvtpk_bf16(p[base + 2], p[base + 3]);
    uint32_t y1 = cvtpk_bf16(p[base + 6], p[base + 7]);
    asm volatile("v_permlane32_swap_b32 %0, %1" : "+v"(x1), "+v"(y1));
    u32x4 r; r[0] = x0; r[1] = x1; r[2] = y0; r[3] = y1;
    if (kh == 0) lo = r; else hi = r;
  }
}

// ------------------------------------------------------------------
// 1) prep: weight MFMA-frag table (bf16) + transposed wo (fp32)
//    wfragb elem (q, kb, lane, j) = w_q[ch = lane&31][c = kb*16 + (lane>>5)*8 + j]
// ------------------------------------------------------------------
__global__ void k_prep(const float* __restrict__ wf1, const float* __restrict__ wg1,
                       const float* __restrict__ wh1, const float* __restrict__ wf2,
                       const float* __restrict__ wg2, const float* __restrict__ wh2,
                       const float* __restrict__ wo1, const float* __restrict__ wo2,
                       uint16_t* __restrict__ wfragb, float* __restrict__ wot) {
  int bid = blockIdx.x;
  if (bid < 192) {
    int idx = bid * 256 + threadIdx.x;                 // < 49152 u16
    int q = idx >> 13, kb = (idx >> 9) & 15, l = (idx >> 3) & 63, j = idx & 7;
    int ch = l & 31, c = kb * 16 + (l >> 5) * 8 + j;
    const float* w = q == 0 ? wf1 : q == 1 ? wg1 : q == 2 ? wh1
                   : q == 3 ? wf2 : q == 4 ? wg2 : wh2;
    wfragb[idx] = (uint16_t)cvtpk_bf16(w[ch * CC + c], 0.f);
  } else {
    int idx = (bid - 192) * 256 + threadIdx.x;         // < 262144
    int o = idx & 255, j = (idx >> 8) & 511, r = idx >> 17;
    const float* wo = r == 0 ? wo1 : wo2;
    wot[idx] = wo[o * 512 + j];
  }
}

// ------------------------------------------------------------------
// 2) effective epilogue weights: Weff = wo * [wv_a; wv_b], beff = bo + wo*bv
// ------------------------------------------------------------------
__global__ void k_weff(const float* __restrict__ wot,
                       const float* __restrict__ wv11, const float* __restrict__ wv12,
                       const float* __restrict__ wv21, const float* __restrict__ wv22,
                       const float* __restrict__ bv11, const float* __restrict__ bv12,
                       const float* __restrict__ bv21, const float* __restrict__ bv22,
                       const float* __restrict__ bo1, const float* __restrict__ bo2,
                       float* __restrict__ weff, float* __restrict__ beff) {
  int bid = blockIdx.x;
  int o = threadIdx.x;
  if (bid < 128) {
    int r = bid >> 6, ch = bid & 63, half = ch >> 5, chp = ch & 31;
    const float* wv = (r == 0) ? (half ? wv12 : wv11) : (half ? wv22 : wv21);
    const float* wocol = wot + ((size_t)r * 512 + half * 256) * 256 + o;
    float a = 0.f;
    for (int c = 0; c < 256; ++c)
      a = fmaf(wocol[(size_t)c * 256], wv[c * CH + chp], a);
    weff[((size_t)r * 64 + ch) * 256 + o] = a;
  } else {
    int r = bid - 128;
    const float* bo  = r == 0 ? bo1 : bo2;
    const float* bva = r == 0 ? bv11 : bv21;
    const float* bvb = r == 0 ? bv12 : bv22;
    const float* wocol = wot + (size_t)r * 512 * 256 + o;
    float a = bo[o];
    for (int c = 0; c < 256; ++c) {
      a = fmaf(wocol[(size_t)c * 256], bva[c], a);
      a = fmaf(wocol[(size_t)(c + 256) * 256], bvb[c], a);
    }
    beff[r * 256 + o] = a;
  }
}

// ------------------------------------------------------------------
// 3) projections via MFMA, zero LDS. 1 wave-task = (proj, b, 32-n tile),
//    K=256 = 16 x mfma_f32_32x32x16_bf16.
//    x-blocks (bid<256): waves = 4 projs {f1,g1,h1,h2} of chunk=bid.
//    y-blocks: 4 waves = 2 chunks x {f2,g2}.
//    Q/K: D = mfma(W, X) -> D[ch][n]; V: D = mfma(X, W) -> D[key][ch].
//    V output instance = ql-2 (h1 -> Vf inst0, h2 -> Vf inst1)  [r5 bugfix]
// ------------------------------------------------------------------
__global__ __launch_bounds__(256) void k_proj(
    const float* __restrict__ x, const float* __restrict__ y,
    const uint16_t* __restrict__ wfragb,
    const float* __restrict__ bf1, const float* __restrict__ bg1, const float* __restrict__ bh1,
    const float* __restrict__ bf2, const float* __restrict__ bg2, const float* __restrict__ bh2,
    uint16_t* __restrict__ Qf, uint16_t* __restrict__ Kf, uint16_t* __restrict__ Vf) {
  int bid = blockIdx.x;
  int w = __builtin_amdgcn_readfirstlane(threadIdx.x >> 6);
  int l = threadIdx.x & 63, l31 = l & 31, l5 = l >> 5;

  int q, ql, b, nt, inst;
  const float* src;
  const float* bias;
  bool isf, isV;
  if (bid < 256) {
    ql = w; b = bid >> 7; nt = bid & 127;
    src = x; inst = 0;
    q = (ql == 3) ? 5 : ql;
    isf = (ql == 0); isV = (ql >= 2);
    bias = ql == 0 ? bf1 : ql == 1 ? bg1 : ql == 2 ? bh1 : bh2;
  } else {
    int u = (bid - 256) * 4 + w;      // 512 y-tasks
    int chunk = u >> 1; ql = u & 1;
    b = chunk >> 7; nt = chunk & 127;
    src = y; inst = 1;
    q = 3 + ql;
    isf = (ql == 0); isV = false;
    bias = ql == 0 ? bf2 : bg2;
  }

  // preload 16 weight frags (16B/lane each)
  const u32x4* wp = (const u32x4*)wfragb + (size_t)q * 16 * 64 + l;
  u32x4 wfr[16];
#pragma unroll
  for (int kb = 0; kb < 16; ++kb) wfr[kb] = wp[kb * 64];

  const float* sp = src + (size_t)b * CC * N + (size_t)(l5 * 8) * N + nt * 32 + l31;
  f32x16 acc;
#pragma unroll
  for (int r = 0; r < 16; ++r) acc[r] = 0.f;

  if (isV) {
#pragma unroll
    for (int kb = 0; kb < 16; ++kb) {
      const float* kp = sp + (size_t)kb * 16 * N;
      float xj[8];
#pragma unroll
      for (int j = 0; j < 8; ++j) xj[j] = kp[(size_t)j * N];
      u32x4 bu;
#pragma unroll
      for (int jh = 0; jh < 4; ++jh) bu[jh] = cvtpk_bf16(xj[2 * jh], xj[2 * jh + 1]);
      acc = __builtin_amdgcn_mfma_f32_32x32x16_bf16(
          __builtin_bit_cast(short8, bu), __builtin_bit_cast(short8, wfr[kb]), acc, 0, 0, 0);
    }
  } else {
#pragma unroll
    for (int kb = 0; kb < 16; ++kb) {
      const float* kp = sp + (size_t)kb * 16 * N;
      float xj[8];
#pragma unroll
      for (int j = 0; j < 8; ++j) xj[j] = kp[(size_t)j * N];
      u32x4 bu;
#pragma unroll
      for (int jh = 0; jh < 4; ++jh) bu[jh] = cvtpk_bf16(xj[2 * jh], xj[2 * jh + 1]);
      acc = __builtin_amdgcn_mfma_f32_32x32x16_bf16(
          __builtin_bit_cast(short8, wfr[kb]), __builtin_bit_cast(short8, bu), acc, 0, 0, 0);
    }
  }

  float p[16];
  if (isV) {
    float bv = bias[l31];                      // D[key][ch=l31]: bias per lane
#pragma unroll
    for (int r = 0; r < 16; ++r) p[r] = acc[r] + bv;
  } else {
#pragma unroll
    for (int r = 0; r < 16; ++r) {
      int crow = (r & 3) + 8 * (r >> 2) + 4 * l5;   // D[ch=crow][n=l31]
      float t = acc[r] + bias[crow];
      p[r] = isf ? t * L2E : t;
    }
  }

  u32x4 lo, hi;
  rows_to_frags(p, lo, hi);

  uint16_t* dstb = isV ? Vf : (isf ? Qf : Kf);
  int oinst = isV ? (ql - 2) : inst;               // [r5 bugfix] h1->inst0, h2->inst1
  int b128 = (oinst * 2 + b) * 128 + nt;
  uint32_t* d0 = (uint32_t*)dstb + (size_t)b128 * 512 + l * 4;
  *(u32x4*)d0 = lo;
  *(u32x4*)(d0 + 256) = hi;
}

// ------------------------------------------------------------------
// 4) MFMA flash attention. Block = 512 thr (8 waves) = one 32-query tile
//    of one (instance, batch). Wave w owns keys [w*512, w*512+512).
//    All loads are frag-layout: base + lane*16B, fully coalesced.
// ------------------------------------------------------------------
__global__ __launch_bounds__(512) void k_attn3(const uint16_t* __restrict__ Qf,
                                               const uint16_t* __restrict__ Kf,
                                               const uint16_t* __restrict__ Vf,
                                               float* __restrict__ aot) {
  __shared__ float redAO[8][32][33];
  __shared__ float redL[8][32];
  int bid = blockIdx.x;
  int qt = bid & 127, b = (bid >> 7) & 1, i = bid >> 8;
  int ia = i >> 1, ik = i & 1;
  int tid = threadIdx.x, w = tid >> 6, l = tid & 63, l31 = l & 31, l5 = l >> 5;

  const uint16_t* Qp = Qf + (size_t)((ia * 2 + b) * 128 + qt) * 1024 + l * 8;
  const uint16_t* Kp = Kf + (size_t)((ik * 2 + b) * 128 + w * 16) * 1024 + l * 8;
  const uint16_t* Vp = Vf + (size_t)((ik * 2 + b) * 128 + w * 16) * 1024 + l * 8;

  short8 bq0 = *(const short8*)(Qp);
  short8 bq1 = *(const short8*)(Qp + 512);

  f32x16 zero16, ao;
#pragma unroll
  for (int r = 0; r < 16; ++r) { zero16[r] = 0.f; ao[r] = 0.f; }
  float lacc = 0.f;

  for (int t = 0; t < 16; ++t) {
    const uint16_t* kt = Kp + t * 1024;
    short8 ak0 = *(const short8*)(kt);
    short8 ak1 = *(const short8*)(kt + 512);
    const uint16_t* vt = Vp + t * 1024;
    short8 bv0 = *(const short8*)(vt);
    short8 bv1 = *(const short8*)(vt + 512);

    f32x16 sa = __builtin_amdgcn_mfma_f32_32x32x16_bf16(ak0, bq0, zero16, 0, 0, 0);
    sa = __builtin_amdgcn_mfma_f32_32x32x16_bf16(ak1, bq1, sa, 0, 0, 0);

    float p[16];
#pragma unroll
    for (int r = 0; r < 16; ++r) p[r] = __builtin_amdgcn_exp2f(sa[r]);

    float t0 = 0.f, t1 = 0.f;
#pragma unroll
    for (int r = 0; r < 8; ++r) { t0 += p[2 * r]; t1 += p[2 * r + 1]; }
    lacc += t0 + t1;

    uint32_t wreg[8];
#pragma unroll
    for (int kh = 0; kh < 2; ++kh) {
      int base = kh * 8;
      uint32_t x0 = cvtpk_bf16(p[base + 0], p[base + 1]);
      uint32_t y0 = cvtpk_bf16(p[base + 4], p[base + 5]);
      asm volatile("v_permlane32_swap_b32 %0, %1" : "+v"(x0), "+v"(y0));
      uint32_t x1 = cvtpk_bf16(p[base + 2], p[base + 3]);
      uint32_t y1 = cvtpk_bf16(p[base + 6], p[base + 7]);
      asm volatile("v_permlane32_swap_b32 %0, %1" : "+v"(x1), "+v"(y1));
      wreg[kh * 4 + 0] = x0; wreg[kh * 4 + 1] = x1; wreg[kh * 4 + 2] = y0; wreg[kh * 4 + 3] = y1;
    }
    short8 pa0, pa1;
    {
      u32x4 u0 = {wreg[0], wreg[1], wreg[2], wreg[3]};
      u32x4 u1 = {wreg[4], wreg[5], wreg[6], wreg[7]};
      pa0 = __builtin_bit_cast(short8, u0);
      pa1 = __builtin_bit_cast(short8, u1);
    }
    ao = __builtin_amdgcn_mfma_f32_32x32x16_bf16(pa0, bv0, ao, 0, 0, 0);
    ao = __builtin_amdgcn_mfma_f32_32x32x16_bf16(pa1, bv1, ao, 0, 0, 0);
  }

  // per-wave partials -> LDS
#pragma unroll
  for (int r = 0; r < 16; ++r) {
    int row = (r & 3) + 8 * (r >> 2) + 4 * l5;       // query within tile
    redAO[w][row][l31] = ao[r];
  }
  lacc += __shfl_xor(lacc, 32);
  if (l < 32) redL[w][l31] = lacc;
  __syncthreads();

  // combine + normalize + transposed write (each thread: q=tid&31, 2 channels)
  int q5 = tid & 31, chb = tid >> 5;                 // chb in [0,16)
  float lsum = 0.f;
#pragma unroll
  for (int ww = 0; ww < 8; ++ww) lsum += redL[ww][q5];
  float inv = __builtin_amdgcn_rcpf(lsum);
  float s0 = 0.f, s1 = 0.f;
#pragma unroll
  for (int ww = 0; ww < 8; ++ww) {
    s0 += redAO[ww][q5][chb];
    s1 += redAO[ww][q5][chb + 16];
  }
  int ib = i * 2 + b;
  float* ob = aot + (size_t)ib * CH * N + qt * 32 + q5;
  ob[(size_t)chb * N] = s0 * inv;
  ob[(size_t)(chb + 16) * N] = s1 * inv;
}

// ------------------------------------------------------------------
// 5) epilogue: out[r][b][o][m] = src + Weff * AO_cat + beff
// ------------------------------------------------------------------
__global__ __launch_bounds__(64) void k_epi(const float* __restrict__ x, const float* __restrict__ y,
                                            const float* __restrict__ aot,
                                            const float* __restrict__ weff,
                                            const float* __restrict__ beff,
                                            float* __restrict__ out) {
  int bid = blockIdx.x;
  int mt = bid & 63, og = (bid >> 6) & 15, b = (bid >> 10) & 1, r = bid >> 11;
  int m = mt * 64 + threadIdx.x;
  int o0 = og * 16;
  const float* src = r == 0 ? x : y;
  const float* A0 = aot + (size_t)(r * 4 + b) * CH * N;        // instance (r, ik=0)
  const float* A1 = aot + (size_t)(r * 4 + 2 + b) * CH * N;    // instance (r, ik=1)
  const float* wrow = weff + (size_t)r * 64 * 256;
  float acc[16];
#pragma unroll
  for (int j = 0; j < 16; ++j) acc[j] = 0.f;
#pragma unroll 4
  for (int ch = 0; ch < 32; ++ch) {
    float av = A0[(size_t)ch * N + m];
    const float* wr = wrow + ch * 256 + o0;
#pragma unroll
    for (int j = 0; j < 16; ++j) acc[j] = fmaf(wr[j], av, acc[j]);
  }
#pragma unroll 4
  for (int ch = 0; ch < 32; ++ch) {
    float av = A1[(size_t)ch * N + m];
    const float* wr = wrow + (32 + ch) * 256 + o0;
#pragma unroll
    for (int j = 0; j < 16; ++j) acc[j] = fmaf(wr[j], av, acc[j]);
  }
  float* outr = out + (size_t)r * 2 * CC * N;
#pragma unroll
  for (int j = 0; j < 16; ++j) {
    int o = o0 + j;
    size_t off = ((size_t)b * CC + o) * N + m;
    outr[off] = src[off] + acc[j] + beff[r * CC + o];
  }
}

extern "C" void kernel_launch(void* const* d_in, const int* in_sizes, int n_in,
                              void* d_out, int out_size, void* d_ws, size_t ws_size,
                              hipStream_t stream) {
  const float* x    = (const float*)d_in[0];
  const float* y    = (const float*)d_in[1];
  const float* wf1  = (const float*)d_in[2];
  const float* bf1  = (const float*)d_in[3];
  const float* wg1  = (const float*)d_in[4];
  const float* bg1  = (const float*)d_in[5];
  const float* wh1  = (const float*)d_in[6];
  const float* bh1  = (const float*)d_in[7];
  const float* wf2  = (const float*)d_in[8];
  const float* bf2  = (const float*)d_in[9];
  const float* wg2  = (const float*)d_in[10];
  const float* bg2  = (const float*)d_in[11];
  const float* wh2  = (const float*)d_in[12];
  const float* bh2  = (const float*)d_in[13];
  const float* wv11 = (const float*)d_in[14];
  const float* bv11 = (const float*)d_in[15];
  const float* wv12 = (const float*)d_in[16];
  const float* bv12 = (const float*)d_in[17];
  const float* wv21 = (const float*)d_in[18];
  const float* bv21 = (const float*)d_in[19];
  const float* wv22 = (const float*)d_in[20];
  const float* bv22 = (const float*)d_in[21];
  const float* wo1  = (const float*)d_in[22];
  const float* bo1  = (const float*)d_in[23];
  const float* wo2  = (const float*)d_in[24];
  const float* bo2  = (const float*)d_in[25];

  float* ws   = (float*)d_ws;
  uint16_t* wfragb = (uint16_t*)(ws + OFF_WFRAG);
  float* wot  = ws + OFF_WOT;
  float* weff = ws + OFF_WEFF;
  float* beff = ws + OFF_BEFF;
  uint16_t* Qf = (uint16_t*)(ws + OFF_QF);
  uint16_t* Kf = (uint16_t*)(ws + OFF_KF);
  uint16_t* Vf = (uint16_t*)(ws + OFF_VF);
  float* aot  = ws + OFF_AOT;
  float* out  = (float*)d_out;

  k_prep<<<1216, 256, 0, stream>>>(wf1, wg1, wh1, wf2, wg2, wh2, wo1, wo2, wfragb, wot);
  k_weff<<<130, 256, 0, stream>>>(wot, wv11, wv12, wv21, wv22,
                                  bv11, bv12, bv21, bv22, bo1, bo2, weff, beff);
  k_proj<<<384, 256, 0, stream>>>(x, y, wfragb, bf1, bg1, bh1, bf2, bg2, bh2, Qf, Kf, Vf);
  k_attn3<<<1024, 512, 0, stream>>>(Qf, Kf, Vf, aot);
  k_epi<<<4096, 64, 0, stream>>>(x, y, aot, weff, beff, out);
}